// Round 10
// baseline (181.149 us; speedup 1.0000x reference)
//
#include <hip/hip_runtime.h>

typedef float f32x4 __attribute__((ext_vector_type(4)));

// db4 reconstruction filters
#define G00 0.23037781330885523f
#define G01 0.7148465705525415f
#define G02 0.6308807679295904f
#define G03 -0.02798376941698385f
#define G04 -0.18703481171888114f
#define G05 0.030841381835986965f
#define G06 0.032883011666982945f
#define G07 -0.010597401784997278f

#define G10 -0.010597401784997278f
#define G11 -0.032883011666982945f
#define G12 0.030841381835986965f
#define G13 0.18703481171888114f
#define G14 -0.02798376941698385f
#define G15 -0.6308807679295904f
#define G16 0.7148465705525415f
#define G17 -0.23037781330885523f

// ===========================================================================
// Level-1 path (N=64): round-7 kernel, unchanged (verified).
// ===========================================================================
template<int LOGN, bool NT>
__device__ __forceinline__ void phaseBC(f32x4* smem, float* __restrict__ out,
                                        int b, int d, int tile, int tid)
{
    constexpr int N = 1 << LOGN;
    constexpr int N4 = N / 4;
    constexpr int LOGN4 = LOGN - 2;
    constexpr int BELEMS = 2 * 32 * N4;
    constexpr int BITER  = BELEMS / 512;

    f32x4 ureg[BITER];
    #pragma unroll
    for (int it = 0; it < BITER; ++it) {
        int e = it * 512 + tid;
        int w4   = e & (N4 - 1);
        int rest = e >> LOGN4;
        int hl   = rest & 31;
        int qq   = rest >> 5;
        int ml = hl >> 1, pp = hl & 1;
        int ro = ml + pp + 3;
        float b0c = pp ? G00 : G01, b1c = pp ? G02 : G03;
        float b2c = pp ? G04 : G05, b3c = pp ? G06 : G07;
        float d0c = pp ? G10 : G11, d1c = pp ? G12 : G13;
        float d2c = pp ? G14 : G15, d3c = pp ? G16 : G17;
        int s0 = 2 * qq, s1 = s0 + 1;
        ureg[it] = b0c * smem[(s0 * 20 + ro    ) * N4 + w4]
                 + b1c * smem[(s0 * 20 + ro - 1) * N4 + w4]
                 + b2c * smem[(s0 * 20 + ro - 2) * N4 + w4]
                 + b3c * smem[(s0 * 20 + ro - 3) * N4 + w4]
                 + d0c * smem[(s1 * 20 + ro    ) * N4 + w4]
                 + d1c * smem[(s1 * 20 + ro - 1) * N4 + w4]
                 + d2c * smem[(s1 * 20 + ro - 2) * N4 + w4]
                 + d3c * smem[(s1 * 20 + ro - 3) * N4 + w4];
    }
    __syncthreads();
    #pragma unroll
    for (int it = 0; it < BITER; ++it) {
        smem[it * 512 + tid] = ureg[it];
    }
    __syncthreads();

    const float* ulf = (const float*)smem;
    float* orow_base = out + (((size_t)b * (2 * N) + d) * (2 * N) + (size_t)32 * tile) * (2 * N);
    for (int e = tid; e < 32 * (N / 2); e += 512) {
        int mw2 = e & (N / 2 - 1);
        int hl  = e >> (LOGN - 1);
        int mw  = mw2 * 2;
        const float* u0 = ulf + (size_t)hl * N;
        const float* u1 = ulf + (size_t)(32 + hl) * N;
        int mm2 = (mw - 2) & (N - 1), mm1 = (mw - 1) & (N - 1);
        int mp1 = (mw + 1) & (N - 1), mp2 = (mw + 2) & (N - 1), mp3 = (mw + 3) & (N - 1);
        float u0m2 = u0[mm2], u0m1 = u0[mm1], u00 = u0[mw];
        float u0p1 = u0[mp1], u0p2 = u0[mp2], u0p3 = u0[mp3];
        float u1m2 = u1[mm2], u1m1 = u1[mm1], u10 = u1[mw];
        float u1p1 = u1[mp1], u1p2 = u1[mp2], u1p3 = u1[mp3];
        f32x4 o;
        o.x = G01*u0p1 + G03*u00  + G05*u0m1 + G07*u0m2
            + G11*u1p1 + G13*u10  + G15*u1m1 + G17*u1m2;
        o.y = G00*u0p2 + G02*u0p1 + G04*u00  + G06*u0m1
            + G10*u1p2 + G12*u1p1 + G14*u10  + G16*u1m1;
        o.z = G01*u0p2 + G03*u0p1 + G05*u00  + G07*u0m1
            + G11*u1p2 + G13*u1p1 + G15*u10  + G17*u1m1;
        o.w = G00*u0p3 + G02*u0p2 + G04*u0p1 + G06*u00
            + G10*u1p3 + G12*u1p2 + G14*u1p1 + G16*u10;
        f32x4* dst = (f32x4*)(orow_base + (size_t)hl * (2 * N)) + mw2;
        if (NT) __builtin_nontemporal_store(o, dst);
        else    *dst = o;
    }
}

template<int LOGN, bool NT>
__global__ __launch_bounds__(512) void idwt3_fused2_k(
    const float* __restrict__ ll, const float* __restrict__ yh,
    float* __restrict__ out, int b0)
{
    constexpr int N = 1 << LOGN;
    constexpr int N4 = N / 4;
    constexpr int LOGN4 = LOGN - 2;
    constexpr int NN = N * N;
    constexpr size_t V = (size_t)N * N * N;
    constexpr int AELEMS = 4 * 20 * N4;
    constexpr int AITER  = (AELEMS + 511) / 512;

    __shared__ f32x4 smem[AELEMS];

    const int tid  = threadIdx.x;
    const int tile = blockIdx.x;
    const int mD   = blockIdx.y;
    const int b    = b0 + (int)blockIdx.z;

    const size_t q0 = (size_t)((mD - 2 + N) & (N - 1)) * NN;
    const size_t q1 = (size_t)((mD - 1 + N) & (N - 1)) * NN;
    const size_t q2 = (size_t)( mD                    ) * NN;
    const size_t q3 = (size_t)((mD + 1) & (N - 1)) * NN;
    const size_t q4 = (size_t)((mD + 2) & (N - 1)) * NN;

    const int h0in = 16 * tile - 2;
    const float* llb = ll + (size_t)b * V;
    const float* yb  = yh + (size_t)b * 7 * V;

    f32x4 treg[AITER];
    #pragma unroll
    for (int it = 0; it < AITER; ++it) {
        int e = it * 512 + tid;
        if (AELEMS % 512 != 0 && e >= AELEMS) continue;
        int w4 = e & (N4 - 1);
        int x  = e >> LOGN4;
        int pr = x / 20;
        int r  = x - 20 * pr;
        int hr = h0in + r;
        if (hr < 0) hr += N;
        if (hr >= N) hr -= N;
        const float* lo_base = (pr == 0) ? llb : (yb + (size_t)(2 * pr - 1) * V);
        const float* hi_base = yb + (size_t)(2 * pr) * V;
        int off = hr * N + w4 * 4;
        const float* lp = lo_base + off;
        const float* hp = hi_base + off;
        f32x4 Lm2 = *(const f32x4*)(lp + q0);
        f32x4 Lm1 = *(const f32x4*)(lp + q1);
        f32x4 L0c = *(const f32x4*)(lp + q2);
        f32x4 Lp1 = *(const f32x4*)(lp + q3);
        f32x4 Lp2 = *(const f32x4*)(lp + q4);
        f32x4 Hm2 = *(const f32x4*)(hp + q0);
        f32x4 Hm1 = *(const f32x4*)(hp + q1);
        f32x4 H0c = *(const f32x4*)(hp + q2);
        f32x4 Hp1 = *(const f32x4*)(hp + q3);
        f32x4 Hp2 = *(const f32x4*)(hp + q4);
        smem[e] = G01*Lp1 + G03*L0c + G05*Lm1 + G07*Lm2
                + G11*Hp1 + G13*H0c + G15*Hm1 + G17*Hm2;
        treg[it] = G00*Lp2 + G02*Lp1 + G04*L0c + G06*Lm1
                 + G10*Hp2 + G12*Hp1 + G14*H0c + G16*Hm1;
    }
    __syncthreads();

    phaseBC<LOGN, NT>(smem, out, b, 2 * mD, tile, tid);
    __syncthreads();

    #pragma unroll
    for (int it = 0; it < AITER; ++it) {
        int e = it * 512 + tid;
        if (AELEMS % 512 != 0 && e >= AELEMS) continue;
        smem[e] = treg[it];
    }
    __syncthreads();

    phaseBC<LOGN, NT>(smem, out, b, 2 * mD + 1, tile, tid);
}

// ===========================================================================
// Level-2 path (N=128): 16-row h-tiles, 256 threads, 24 KB LDS -> 6 blocks/CU.
// tl[4][12][32] f32x4 (1536); ul[2][16] rows padded stride 33 f32x4 (1056,
// overlaid on tl). d-parity pairing, sliding-window B, coalesced NT C stores.
// ===========================================================================
__device__ __forceinline__ void phaseBC_l2b(f32x4* smem, float* __restrict__ out,
                                            int b, int d, int tile, int tid)
{
    // ---- Phase B: 2 slots/thread; slot (s,qq,w4): rows s..s+4 -> hl=2s,2s+1
    f32x4 uacc[4];
    #pragma unroll
    for (int k = 0; k < 2; ++k) {
        int sl = tid + k * 256;
        int w4 = sl & 31;
        int qq = (sl >> 5) & 1;
        int s  = sl >> 6;                        // [0,8)
        const f32x4* t0 = smem + ((2 * qq) * 12 + s) * 32 + w4;   // lo tile
        const f32x4* t1 = t0 + 12 * 32;                           // hi tile
        f32x4 r0 = t0[0], r1 = t0[32], r2 = t0[64], r3 = t0[96], r4 = t0[128];
        f32x4 e0 = t1[0], e1 = t1[32], e2 = t1[64], e3 = t1[96], e4 = t1[128];
        // hl=2s (p=0): rows s+3..s ; hl=2s+1 (p=1): rows s+4..s+1
        uacc[2 * k]     = G01*r3 + G03*r2 + G05*r1 + G07*r0
                        + G11*e3 + G13*e2 + G15*e1 + G17*e0;
        uacc[2 * k + 1] = G00*r4 + G02*r3 + G04*r2 + G06*r1
                        + G10*e4 + G12*e3 + G14*e2 + G16*e1;
    }
    __syncthreads();                             // all tl reads complete
    #pragma unroll
    for (int k = 0; k < 2; ++k) {
        int sl = tid + k * 256;
        int w4 = sl & 31;
        int qq = (sl >> 5) & 1;
        int s  = sl >> 6;
        f32x4* ub = smem + ((qq * 16 + 2 * s) * 33 + w4);
        ub[0]  = uacc[2 * k];
        ub[33] = uacc[2 * k + 1];
    }
    __syncthreads();

    // ---- Phase C: coalesced NT b128 stores; stride-2 scalar LDS reads
    const float* ulf = (const float*)smem;
    float* orow_base = out + (((size_t)b * 256 + d) * 256 + (size_t)16 * tile) * 256;
    #pragma unroll
    for (int it = 0; it < 4; ++it) {
        int e = it * 256 + tid;
        int mw2 = e & 63;
        int hl  = e >> 6;                        // [0,16)
        int mw  = mw2 * 2;
        const float* u0 = ulf + (size_t)hl * 132;          // ul[0][hl]
        const float* u1 = ulf + (size_t)(16 + hl) * 132;   // ul[1][hl]
        int mm2 = (mw - 2) & 127, mm1 = (mw - 1) & 127;
        int mp1 = (mw + 1) & 127, mp2 = (mw + 2) & 127, mp3 = (mw + 3) & 127;
        float u0m2 = u0[mm2], u0m1 = u0[mm1], u00 = u0[mw];
        float u0p1 = u0[mp1], u0p2 = u0[mp2], u0p3 = u0[mp3];
        float u1m2 = u1[mm2], u1m1 = u1[mm1], u10 = u1[mw];
        float u1p1 = u1[mp1], u1p2 = u1[mp2], u1p3 = u1[mp3];
        f32x4 o;
        o.x = G01*u0p1 + G03*u00  + G05*u0m1 + G07*u0m2
            + G11*u1p1 + G13*u10  + G15*u1m1 + G17*u1m2;
        o.y = G00*u0p2 + G02*u0p1 + G04*u00  + G06*u0m1
            + G10*u1p2 + G12*u1p1 + G14*u10  + G16*u1m1;
        o.z = G01*u0p2 + G03*u0p1 + G05*u00  + G07*u0m1
            + G11*u1p2 + G13*u1p1 + G15*u10  + G17*u1m1;
        o.w = G00*u0p3 + G02*u0p2 + G04*u0p1 + G06*u00
            + G10*u1p3 + G12*u1p2 + G14*u1p1 + G16*u10;
        f32x4* dst = (f32x4*)(orow_base + (size_t)hl * 256) + mw2;
        __builtin_nontemporal_store(o, dst);
    }
}

__global__ __launch_bounds__(256) void idwt3_l2b_k(
    const float* __restrict__ ll, const float* __restrict__ yh,
    float* __restrict__ out)
{
    constexpr int N = 128;
    constexpr int NN = N * N;
    constexpr size_t V = (size_t)N * N * N;

    __shared__ f32x4 smem[1536];                 // tl[4][12][32]; reused as padded ul

    const int tid  = threadIdx.x;
    const int tile = blockIdx.x;                 // 16 h-tiles of 16 output rows
    const int mD   = blockIdx.y;                 // 128 d-pairs
    const int b    = blockIdx.z;                 // 4 batches

    const size_t q0 = (size_t)((mD - 2 + N) & (N - 1)) * NN;
    const size_t q1 = (size_t)((mD - 1 + N) & (N - 1)) * NN;
    const size_t q2 = (size_t)( mD                    ) * NN;
    const size_t q3 = (size_t)((mD + 1) & (N - 1)) * NN;
    const size_t q4 = (size_t)((mD + 2) & (N - 1)) * NN;

    const int h0in = 8 * tile - 2;               // first halo h-row (wrapped)
    const float* llb = ll + (size_t)b * V;
    const float* yb  = yh + (size_t)b * 7 * V;

    f32x4 treg[6];
    #pragma unroll
    for (int it = 0; it < 6; ++it) {
        int e = it * 256 + tid;
        int w4 = e & 31;
        int x  = e >> 5;                         // pr*12 + r, [0,48)
        int pr = x / 12;
        int r  = x - 12 * pr;
        int hr = h0in + r;
        if (hr < 0) hr += N;
        if (hr >= N) hr -= N;
        const float* lo_base = (pr == 0) ? llb : (yb + (size_t)(2 * pr - 1) * V);
        const float* hi_base = yb + (size_t)(2 * pr) * V;
        int off = hr * N + w4 * 4;
        const float* lp = lo_base + off;
        const float* hp = hi_base + off;
        f32x4 Lm2 = *(const f32x4*)(lp + q0);
        f32x4 Lm1 = *(const f32x4*)(lp + q1);
        f32x4 L0c = *(const f32x4*)(lp + q2);
        f32x4 Lp1 = *(const f32x4*)(lp + q3);
        f32x4 Lp2 = *(const f32x4*)(lp + q4);
        f32x4 Hm2 = *(const f32x4*)(hp + q0);
        f32x4 Hm1 = *(const f32x4*)(hp + q1);
        f32x4 H0c = *(const f32x4*)(hp + q2);
        f32x4 Hp1 = *(const f32x4*)(hp + q3);
        f32x4 Hp2 = *(const f32x4*)(hp + q4);
        smem[e] = G01*Lp1 + G03*L0c + G05*Lm1 + G07*Lm2
                + G11*Hp1 + G13*H0c + G15*Hm1 + G17*Hm2;
        treg[it] = G00*Lp2 + G02*Lp1 + G04*L0c + G06*Lm1
                 + G10*Hp2 + G12*Hp1 + G14*H0c + G16*Hm1;
    }
    __syncthreads();

    phaseBC_l2b(smem, out, b, 2 * mD, tile, tid);
    __syncthreads();

    #pragma unroll
    for (int it = 0; it < 6; ++it) smem[it * 256 + tid] = treg[it];
    __syncthreads();

    phaseBC_l2b(smem, out, b, 2 * mD + 1, tile, tid);
}

// ===========================================================================

extern "C" void kernel_launch(void* const* d_in, const int* in_sizes, int n_in,
                              void* d_out, int out_size, void* d_ws, size_t ws_size,
                              hipStream_t stream)
{
    const float* yl  = (const float*)d_in[0];   // (4,1,64,64,64)
    const float* yh1 = (const float*)d_in[1];   // (4,7,128,128,128)
    const float* yh2 = (const float*)d_in[2];   // (4,7,64,64,64)
    float* outf = (float*)d_out;                // (4,1,256,256,256)
    float* ll1  = (float*)d_ws;                 // (4,128,128,128) scratch

    // Level 1 (n=64 -> 128): round-7 kernel, all batches
    idwt3_fused2_k<6, false><<<dim3(4, 64, 4), 512, 0, stream>>>(yl, yh2, ll1, 0);

    // Level 2 (n=128 -> 256): 16-row-tile kernel, 6 blocks/CU, one launch
    idwt3_l2b_k<<<dim3(16, 128, 4), 256, 0, stream>>>(ll1, yh1, outf);
}